// Round 1
// baseline (190.785 us; speedup 1.0000x reference)
//
#include <hip/hip_runtime.h>
#include <math.h>

namespace {
constexpr int kN = 22;
constexpr int kF = 448;
constexpr int kNP = kN * kN;        // 484
constexpr int kXStr = kF + 1;       // 449: 449%32==1 -> row-strided LDS reads spread banks
constexpr int kVStr = 65;           // 65%32==1 -> same trick for the 64-wide vectors
constexpr int kThreads = 512;

// flat LDS layout in floats (no per-array alignment padding; total 16382 fl = 65528 B <= 64 KiB)
constexpr int oXS  = 0;                    // x tile 22x449; reused for sw2 (2048 fl) in phase 2
constexpr int oA1  = oXS + kN * kXStr;     // a1 = x@cw1[:448]   (+cb1 folded)
constexpr int oA2  = oA1 + kN * kVStr;     // a2 = x@cw1[448:]
constexpr int oU1  = oA2 + kN * kVStr;     // u1 = emb@sw1[0:64]  + x@sw1[128:576] (+sb1 folded)
constexpr int oU2  = oU1 + kN * kVStr;     // u2 = emb@sw1[64:128]+ x@sw1[576:1024]
constexpr int oG   = oU2 + kN * kVStr;     // corr matrix 484
constexpr int oMU  = oG + kNP;             // row means 22
constexpr int oIS  = oMU + kN;             // 1/(std+1e-8) 22
constexpr int oLNG = oIS + kN;             // 64
constexpr int oLNB = oLNG + 64;            // 64
constexpr int oCW2 = oLNB + 64;            // 64
constexpr int oSW3 = oCW2 + 64;            // 32
constexpr int oSB2 = oSW3 + 32;            // 32
constexpr int kSmem = oSB2 + 32;           // 16382
}

__global__ __launch_bounds__(kThreads) void hgc_fused(
    const float* __restrict__ x,
    const float* __restrict__ cw1, const float* __restrict__ cb1,
    const float* __restrict__ cw2, const float* __restrict__ cb2,
    const float* __restrict__ emb,
    const float* __restrict__ sw1, const float* __restrict__ sb1,
    const float* __restrict__ ln_g, const float* __restrict__ ln_b,
    const float* __restrict__ sw2, const float* __restrict__ sb2,
    const float* __restrict__ sw3, const float* __restrict__ sb3,
    const float* __restrict__ thr, const float* __restrict__ alpha_p,
    float* __restrict__ out)
{
    __shared__ __align__(16) float sm[kSmem];
    const int tid = threadIdx.x;
    const int b   = blockIdx.x;

    // ---- stage x tile (padded stride) + small consts ----
    {
        const float* xb = x + (size_t)b * (kN * kF);
        for (int idx = tid; idx < kN * kF; idx += kThreads) {
            const int r = idx / kF;
            const int f = idx - r * kF;
            sm[oXS + r * kXStr + f] = xb[idx];
        }
        if (tid < 64) {
            sm[oLNG + tid] = ln_g[tid];
            sm[oLNB + tid] = ln_b[tid];
            sm[oCW2 + tid] = cw2[tid];
        } else if (tid < 96) {
            sm[oSW3 + tid - 64] = sw3[tid - 64];
            sm[oSB2 + tid - 64] = sb2[tid - 64];
        }
    }
    __syncthreads();

    // ---- phase 1a: per-row mean and 1/(unbiased std + 1e-8) ----
    {
        const int wid = tid >> 6, lane = tid & 63;
        for (int r = wid; r < kN; r += 8) {
            const float* row = sm + oXS + r * kXStr;
            float s = 0.f;
            #pragma unroll
            for (int c = 0; c < 7; ++c) s += row[c * 64 + lane];
            #pragma unroll
            for (int o = 32; o; o >>= 1) s += __shfl_xor(s, o, 64);
            const float mean = s * (1.f / 448.f);
            float ss = 0.f;
            #pragma unroll
            for (int c = 0; c < 7; ++c) { const float d = row[c * 64 + lane] - mean; ss = fmaf(d, d, ss); }
            #pragma unroll
            for (int o = 32; o; o >>= 1) ss += __shfl_xor(ss, o, 64);
            if (lane == 0) {
                sm[oMU + r] = mean;
                sm[oIS + r] = 1.f / (sqrtf(ss * (1.f / 447.f)) + 1e-8f);   // torch/jnp ddof=1
            }
        }
    }
    __syncthreads();

    // ---- phase 1b: per-row projections a1,a2,u1,u2 (float4 over output dim) ----
    {
        const int q = tid & 15;       // owns outputs 4q..4q+3
        const int r = tid >> 4;       // row slot 0..31 (22 active)
        if (r < kN) {
            const float4* c4 = (const float4*)cw1;   // (896,64) row-major
            const float4* s4 = (const float4*)sw1;   // (1024,64) row-major
            float4 A1 = {0,0,0,0}, A2 = {0,0,0,0}, U1 = {0,0,0,0}, U2 = {0,0,0,0};
            const float* row = sm + oXS + r * kXStr;
            for (int f = 0; f < kF; ++f) {
                const float xv = row[f];              // LDS broadcast within the 16-lane group
                float4 w;
                w = c4[f * 16 + q];
                A1.x = fmaf(xv, w.x, A1.x); A1.y = fmaf(xv, w.y, A1.y);
                A1.z = fmaf(xv, w.z, A1.z); A1.w = fmaf(xv, w.w, A1.w);
                w = c4[(kF + f) * 16 + q];
                A2.x = fmaf(xv, w.x, A2.x); A2.y = fmaf(xv, w.y, A2.y);
                A2.z = fmaf(xv, w.z, A2.z); A2.w = fmaf(xv, w.w, A2.w);
                w = s4[(128 + f) * 16 + q];
                U1.x = fmaf(xv, w.x, U1.x); U1.y = fmaf(xv, w.y, U1.y);
                U1.z = fmaf(xv, w.z, U1.z); U1.w = fmaf(xv, w.w, U1.w);
                w = s4[(576 + f) * 16 + q];
                U2.x = fmaf(xv, w.x, U2.x); U2.y = fmaf(xv, w.y, U2.y);
                U2.z = fmaf(xv, w.z, U2.z); U2.w = fmaf(xv, w.w, U2.w);
            }
            for (int h = 0; h < 64; ++h) {
                const float ev = emb[r * 64 + h];
                float4 w;
                w = s4[h * 16 + q];
                U1.x = fmaf(ev, w.x, U1.x); U1.y = fmaf(ev, w.y, U1.y);
                U1.z = fmaf(ev, w.z, U1.z); U1.w = fmaf(ev, w.w, U1.w);
                w = s4[(64 + h) * 16 + q];
                U2.x = fmaf(ev, w.x, U2.x); U2.y = fmaf(ev, w.y, U2.y);
                U2.z = fmaf(ev, w.z, U2.z); U2.w = fmaf(ev, w.w, U2.w);
            }
            const int t0 = q * 4;
            float* pa1 = sm + oA1 + r * kVStr + t0;
            float* pa2 = sm + oA2 + r * kVStr + t0;
            float* pu1 = sm + oU1 + r * kVStr + t0;
            float* pu2 = sm + oU2 + r * kVStr + t0;
            pa1[0] = A1.x + cb1[t0+0]; pa1[1] = A1.y + cb1[t0+1];
            pa1[2] = A1.z + cb1[t0+2]; pa1[3] = A1.w + cb1[t0+3];
            pa2[0] = A2.x; pa2[1] = A2.y; pa2[2] = A2.z; pa2[3] = A2.w;
            pu1[0] = U1.x + sb1[t0+0]; pu1[1] = U1.y + sb1[t0+1];
            pu1[2] = U1.z + sb1[t0+2]; pu1[3] = U1.w + sb1[t0+3];
            pu2[0] = U2.x; pu2[1] = U2.y; pu2[2] = U2.z; pu2[3] = U2.w;
        }
    }

    // ---- phase 1c: correlation |xn_i . xn_j| / F  (no barrier needed: disjoint writes) ----
    if (tid < kNP) {
        const int i = tid / kN;
        const int j = tid - i * kN;
        const float* ri = sm + oXS + i * kXStr;
        const float* rj = sm + oXS + j * kXStr;
        float dot = 0.f;
        for (int f = 0; f < kF; ++f) dot = fmaf(ri[f], rj[f], dot);
        const float c = (dot - 448.f * sm[oMU + i] * sm[oMU + j])
                        * sm[oIS + i] * sm[oIS + j] * (1.f / 448.f);
        sm[oG + tid] = fabsf(c);
    }
    __syncthreads();

    // ---- phase 1d: x tile dead; reuse its LDS for sw2 (64x32) ----
    for (int idx = tid; idx < 64 * 32; idx += kThreads) sm[oXS + idx] = sw2[idx];
    __syncthreads();

    // ---- phase 2: one thread per (i,j) pair ----
    if (tid < kNP) {
        const int i = tid / kN;
        const int j = tid - i * kN;

        // correlation edge weight: sigmoid(relu(a1_i + a2_j) . cw2 + cb2)
        const float* pa1 = sm + oA1 + i * kVStr;
        const float* pa2 = sm + oA2 + j * kVStr;
        float zc = 0.f;
        #pragma unroll 4
        for (int k = 0; k < 64; ++k) {
            float h = pa1[k] + pa2[k];
            h = fmaxf(h, 0.f);
            zc = fmaf(h, sm[oCW2 + k], zc);
        }
        const float wc = 1.f / (1.f + __expf(-(zc + cb2[0])));
        const float gcorr = fmaf(sm[oG + tid], wc, (i == j) ? 1.f : 0.f);

        float gsem;
        if (i == j) {
            gsem = 1.f;   // diag: adj=0, +I
        } else {
            // reference keeps only upper-triangular w_sem and mirrors -> use (lo,hi)
            const int lo = (i < j) ? i : j;
            const int hi = (i < j) ? j : i;
            const float* pu1 = sm + oU1 + lo * kVStr;
            const float* pu2 = sm + oU2 + hi * kVStr;
            float mean = 0.f;
            #pragma unroll 4
            for (int k = 0; k < 64; ++k) mean += pu1[k] + pu2[k];
            mean *= (1.f / 64.f);
            float ss = 0.f;
            #pragma unroll 4
            for (int k = 0; k < 64; ++k) { const float d = pu1[k] + pu2[k] - mean; ss = fmaf(d, d, ss); }
            const float rstd = rsqrtf(ss * (1.f / 64.f) + 1e-5f);
            float acc[32];
            #pragma unroll
            for (int o = 0; o < 32; ++o) acc[o] = 0.f;
            for (int k = 0; k < 64; ++k) {
                float v = (pu1[k] + pu2[k] - mean) * rstd;
                v = fmaf(v, sm[oLNG + k], sm[oLNB + k]);
                v = fmaxf(v, 0.f);
                const float4* w4 = (const float4*)(sm + oXS + k * 32);  // sw2 row k, 128B aligned
                #pragma unroll
                for (int o8 = 0; o8 < 8; ++o8) {
                    const float4 w = w4[o8];
                    acc[o8*4+0] = fmaf(v, w.x, acc[o8*4+0]);
                    acc[o8*4+1] = fmaf(v, w.y, acc[o8*4+1]);
                    acc[o8*4+2] = fmaf(v, w.z, acc[o8*4+2]);
                    acc[o8*4+3] = fmaf(v, w.w, acc[o8*4+3]);
                }
            }
            float z2 = 0.f;
            #pragma unroll
            for (int o = 0; o < 32; ++o)
                z2 = fmaf(fmaxf(acc[o] + sm[oSB2 + o], 0.f), sm[oSW3 + o], z2);
            // accurate expf here: this sigmoid feeds a hard threshold compare
            const float ws = 1.f / (1.f + expf(-(z2 + sb3[0])));
            const float tt = 1.f / (1.f + expf(-thr[0]));
            gsem = (ws > tt) ? ws : 0.f;
        }
        const float alpha = 1.f / (1.f + __expf(-alpha_p[0]));
        out[(size_t)b * kNP + tid] = fmaf(alpha, gcorr, (1.f - alpha) * gsem);
    }
}

extern "C" void kernel_launch(void* const* d_in, const int* in_sizes, int n_in,
                              void* d_out, int out_size, void* d_ws, size_t ws_size,
                              hipStream_t stream)
{
    const float* x     = (const float*)d_in[0];
    const float* cw1   = (const float*)d_in[1];
    const float* cb1   = (const float*)d_in[2];
    const float* cw2   = (const float*)d_in[3];
    const float* cb2   = (const float*)d_in[4];
    const float* emb   = (const float*)d_in[5];
    const float* sw1   = (const float*)d_in[6];
    const float* sb1   = (const float*)d_in[7];
    const float* ln_g  = (const float*)d_in[8];
    const float* ln_b  = (const float*)d_in[9];
    const float* sw2   = (const float*)d_in[10];
    const float* sb2   = (const float*)d_in[11];
    const float* sw3   = (const float*)d_in[12];
    const float* sb3   = (const float*)d_in[13];
    const float* thr   = (const float*)d_in[14];
    const float* alpha = (const float*)d_in[15];
    float* out = (float*)d_out;
    const int B = in_sizes[0] / (22 * 448);
    hipLaunchKernelGGL(hgc_fused, dim3(B), dim3(kThreads), 0, stream,
                       x, cw1, cb1, cw2, cb2, emb, sw1, sb1, ln_g, ln_b,
                       sw2, sb2, sw3, sb3, thr, alpha, out);
}

// Round 2
// 165.135 us; speedup vs baseline: 1.1553x; 1.1553x over previous
//
#include <hip/hip_runtime.h>
#include <math.h>

namespace {
constexpr int kN = 22;
constexpr int kF = 448;
constexpr int kNP = kN * kN;         // 484
constexpr int kXStr = kF + 1;        // 449 (bank-spread)
constexpr int kWsStrideB = 6144;     // floats per batch element in workspace
// per-b workspace float offsets
constexpr int wA1 = 0;               // a1 = x@cw1[:448] + cb1      (22x64)
constexpr int wA2 = 1408;            // a2 = x@cw1[448:]            (22x64)
constexpr int wU1 = 2816;            // u1 = emb@sw1[0:64]+x@sw1[128:576]+sb1
constexpr int wU2 = 4224;            // u2 = emb@sw1[64:128]+x@sw1[576:1024]
constexpr int wG  = 5632;            // |corr| (22x22)
constexpr int kPStr = 68;            // k2 staged row stride (16B-aligned, 68%32==4)
}

// ---------------- kernel 1: per-(b, row-half) stats + projections + corr ----
__global__ __launch_bounds__(512) void hgc_k1(
    const float* __restrict__ x,
    const float* __restrict__ cw1, const float* __restrict__ cb1,
    const float* __restrict__ emb,
    const float* __restrict__ sw1, const float* __restrict__ sb1,
    float* __restrict__ ws)
{
    __shared__ __align__(16) float sm[kN * kXStr + 2 * kN];
    float* smu = sm + kN * kXStr;
    float* sis = smu + kN;
    const int tid  = threadIdx.x;
    const int b    = blockIdx.x >> 1;
    const int half = blockIdx.x & 1;
    const int r0   = half * 11;

    // stage x tile (float4 global loads, scalar LDS stores into padded rows)
    {
        const float4* xb4 = (const float4*)(x + (size_t)b * (kN * kF));
        for (int idx = tid; idx < kN * kF / 4; idx += 512) {
            const float4 v = xb4[idx];
            const int r = idx / 112;            // 448/4 = 112 float4 per row
            const int k = (idx - r * 112) * 4;
            float* d = sm + r * kXStr + k;
            d[0] = v.x; d[1] = v.y; d[2] = v.z; d[3] = v.w;
        }
    }
    __syncthreads();

    // per-row mean and 1/(unbiased std + 1e-8), all 22 rows
    {
        const int wid = tid >> 6, lane = tid & 63;
        for (int r = wid; r < kN; r += 8) {
            const float* row = sm + r * kXStr;
            float s = 0.f;
            #pragma unroll
            for (int c = 0; c < 7; ++c) s += row[c * 64 + lane];
            #pragma unroll
            for (int o = 32; o; o >>= 1) s += __shfl_xor(s, o, 64);
            const float mean = s * (1.f / 448.f);
            float ss = 0.f;
            #pragma unroll
            for (int c = 0; c < 7; ++c) { const float d = row[c * 64 + lane] - mean; ss = fmaf(d, d, ss); }
            #pragma unroll
            for (int o = 32; o; o >>= 1) ss += __shfl_xor(ss, o, 64);
            if (lane == 0) {
                smu[r] = mean;
                sis[r] = 1.f / (sqrtf(ss * (1.f / 447.f)) + 1e-8f);  // ddof=1
            }
        }
    }
    __syncthreads();

    float* wsb = ws + (size_t)b * kWsStrideB;

    if (tid < 352) {
        // projections: thread = (rr 0..10, g 0..1, q 0..15); branch-free weight select
        const int rr = tid >> 5, g = (tid >> 4) & 1, q = tid & 15;
        const int r = r0 + rr;
        const float4* w0 = g ? ((const float4*)sw1) + 128 * 16 : (const float4*)cw1;
        const float4* w1 = g ? ((const float4*)sw1) + 576 * 16 : ((const float4*)cw1) + 448 * 16;
        const float* row = sm + r * kXStr;
        float4 P = {0,0,0,0}, Q = {0,0,0,0};
        for (int f = 0; f < kF; ++f) {
            const float xv = row[f];
            float4 w = w0[f * 16 + q];
            P.x = fmaf(xv, w.x, P.x); P.y = fmaf(xv, w.y, P.y);
            P.z = fmaf(xv, w.z, P.z); P.w = fmaf(xv, w.w, P.w);
            w = w1[f * 16 + q];
            Q.x = fmaf(xv, w.x, Q.x); Q.y = fmaf(xv, w.y, Q.y);
            Q.z = fmaf(xv, w.z, Q.z); Q.w = fmaf(xv, w.w, Q.w);
        }
        if (g) {   // semantic branch adds emb part (half-wave divergence, 64 iters)
            const float4* s4 = (const float4*)sw1;
            for (int h = 0; h < 64; ++h) {
                const float ev = emb[r * 64 + h];
                float4 w = s4[h * 16 + q];
                P.x = fmaf(ev, w.x, P.x); P.y = fmaf(ev, w.y, P.y);
                P.z = fmaf(ev, w.z, P.z); P.w = fmaf(ev, w.w, P.w);
                w = s4[(64 + h) * 16 + q];
                Q.x = fmaf(ev, w.x, Q.x); Q.y = fmaf(ev, w.y, Q.y);
                Q.z = fmaf(ev, w.z, Q.z); Q.w = fmaf(ev, w.w, Q.w);
            }
        }
        const int t0 = q * 4;
        const float* bias = g ? sb1 : cb1;
        P.x += bias[t0]; P.y += bias[t0 + 1]; P.z += bias[t0 + 2]; P.w += bias[t0 + 3];
        *((float4*)(wsb + (g ? wU1 : wA1) + r * 64 + t0)) = P;
        *((float4*)(wsb + (g ? wU2 : wA2) + r * 64 + t0)) = Q;
    } else {
        // corr rows r0..r0+10 on the otherwise-idle waves (runs concurrently)
        for (int p = tid - 352; p < 11 * kN; p += 160) {
            const int pi = p / 22;
            const int i = r0 + pi, j = p - pi * 22;
            const float* ri = sm + i * kXStr;
            const float* rj = sm + j * kXStr;
            float dot = 0.f;
            for (int f = 0; f < kF; ++f) dot = fmaf(ri[f], rj[f], dot);
            const float c = (dot - 448.f * smu[i] * smu[j]) * sis[i] * sis[j] * (1.f / 448.f);
            wsb[wG + i * 22 + j] = fabsf(c);
        }
    }
}

// ---------------- kernel 2: 8 lanes per (i,j) pair, 32 pairs/block ----------
__global__ __launch_bounds__(256) void hgc_k2(
    const float* __restrict__ ws,
    const float* __restrict__ cw2, const float* __restrict__ cb2,
    const float* __restrict__ sw2, const float* __restrict__ sb2,
    const float* __restrict__ sw3, const float* __restrict__ sb3,
    const float* __restrict__ ln_g, const float* __restrict__ ln_b,
    const float* __restrict__ thr, const float* __restrict__ alpha_p,
    float* __restrict__ out)
{
    __shared__ __align__(16) float sp[4 * kN * kPStr];   // a1|a2|u1|u2, padded rows
    __shared__ float sg[kNP];
    __shared__ __align__(16) float sw2s[2048];
    __shared__ float scw2[64], slng[64], slnb[64], ssw3[32], ssb2[32];
    __shared__ float vbuf[32 * 66];

    const int tid = threadIdx.x;
    const int b   = blockIdx.x >> 4;     // 16 blocks per batch element
    const int pb  = blockIdx.x & 15;
    const float* wsb = ws + (size_t)b * kWsStrideB;

    // stage the four 22x64 projection arrays into padded LDS rows
    #pragma unroll
    for (int a = 0; a < 4; ++a) {
        const float4* src = (const float4*)(wsb + a * 1408);
        float* dst = sp + a * kN * kPStr;
        for (int idx = tid; idx < 352; idx += 256) {
            const int r = idx >> 4, k = (idx & 15) * 4;
            *((float4*)(dst + r * kPStr + k)) = src[idx];
        }
    }
    for (int idx = tid; idx < kNP; idx += 256) sg[idx] = wsb[wG + idx];
    {
        const float4* s4 = (const float4*)sw2;
        for (int idx = tid; idx < 512; idx += 256)
            *((float4*)(sw2s + idx * 4)) = s4[idx];
    }
    if (tid < 64)       { scw2[tid] = cw2[tid]; slng[tid] = ln_g[tid]; slnb[tid] = ln_b[tid]; }
    else if (tid < 96)  { ssw3[tid - 64] = sw3[tid - 64]; }
    else if (tid < 128) { ssb2[tid - 96] = sb2[tid - 96]; }
    __syncthreads();

    const int pl = tid >> 3;             // local pair 0..31
    const int t  = tid & 7;              // lane within pair group
    const int p_ = pb * 32 + pl;
    const bool valid = p_ < kNP;
    const int p = valid ? p_ : 0;
    const int i = p / 22, j = p - (p / 22) * 22;

    const float* sa1 = sp;
    const float* sa2 = sp + kN * kPStr;
    const float* su1 = sp + 2 * kN * kPStr;
    const float* su2 = sp + 3 * kN * kPStr;

    // correlation edge weight: sigmoid(relu(a1_i + a2_j) . cw2 + cb2)
    float zc = 0.f;
    {
        const float* pa1 = sa1 + i * kPStr + t * 8;
        const float* pa2 = sa2 + j * kPStr + t * 8;
        #pragma unroll
        for (int c = 0; c < 8; ++c) {
            const float h = fmaxf(pa1[c] + pa2[c], 0.f);
            zc = fmaf(h, scw2[t * 8 + c], zc);
        }
        zc += __shfl_xor(zc, 1, 64); zc += __shfl_xor(zc, 2, 64); zc += __shfl_xor(zc, 4, 64);
    }
    const float wc = 1.f / (1.f + __expf(-(zc + cb2[0])));

    // semantic branch (computed unconditionally; diag result overridden)
    const int lo = (i < j) ? i : j, hi = (i < j) ? j : i;
    const float* pu1 = su1 + lo * kPStr + t * 8;
    const float* pu2 = su2 + hi * kPStr + t * 8;
    float raw[8];
    float s1 = 0.f;
    #pragma unroll
    for (int c = 0; c < 8; ++c) { raw[c] = pu1[c] + pu2[c]; s1 += raw[c]; }
    s1 += __shfl_xor(s1, 1, 64); s1 += __shfl_xor(s1, 2, 64); s1 += __shfl_xor(s1, 4, 64);
    const float mean = s1 * (1.f / 64.f);
    float s2 = 0.f;
    #pragma unroll
    for (int c = 0; c < 8; ++c) { const float d = raw[c] - mean; s2 = fmaf(d, d, s2); }
    s2 += __shfl_xor(s2, 1, 64); s2 += __shfl_xor(s2, 2, 64); s2 += __shfl_xor(s2, 4, 64);
    const float rstd = rsqrtf(s2 * (1.f / 64.f) + 1e-5f);
    {
        float* vb = vbuf + pl * 66 + t * 8;
        #pragma unroll
        for (int c = 0; c < 8; ++c) {
            const int k = t * 8 + c;
            float v = (raw[c] - mean) * rstd;
            v = fmaf(v, slng[k], slnb[k]);
            vb[c] = fmaxf(v, 0.f);
        }
    }
    __syncthreads();   // vbuf visibility (intra-wave, but keep ordering explicit)

    // 64x32 GEMV: lane owns outputs o = t*4 .. t*4+3
    float4 acc = {0,0,0,0};
    {
        const float* vb = vbuf + pl * 66;
        for (int k = 0; k < 64; ++k) {
            const float v = vb[k];
            const float4 w = *((const float4*)(sw2s + k * 32 + t * 4));
            acc.x = fmaf(v, w.x, acc.x); acc.y = fmaf(v, w.y, acc.y);
            acc.z = fmaf(v, w.z, acc.z); acc.w = fmaf(v, w.w, acc.w);
        }
    }
    float z2;
    {
        const int o0 = t * 4;
        z2  = fmaxf(acc.x + ssb2[o0 + 0], 0.f) * ssw3[o0 + 0];
        z2 += fmaxf(acc.y + ssb2[o0 + 1], 0.f) * ssw3[o0 + 1];
        z2 += fmaxf(acc.z + ssb2[o0 + 2], 0.f) * ssw3[o0 + 2];
        z2 += fmaxf(acc.w + ssb2[o0 + 3], 0.f) * ssw3[o0 + 3];
        z2 += __shfl_xor(z2, 1, 64); z2 += __shfl_xor(z2, 2, 64); z2 += __shfl_xor(z2, 4, 64);
    }

    if (valid && t == 0) {
        float gsem;
        if (i == j) {
            gsem = 1.f;
        } else {
            // accurate expf: this sigmoid feeds a hard threshold compare
            const float wsem = 1.f / (1.f + expf(-(z2 + sb3[0])));
            const float tt   = 1.f / (1.f + expf(-thr[0]));
            gsem = (wsem > tt) ? wsem : 0.f;
        }
        const float alpha = 1.f / (1.f + __expf(-alpha_p[0]));
        const float gcorr = fmaf(sg[p], wc, (i == j) ? 1.f : 0.f);
        out[(size_t)b * kNP + p] = fmaf(alpha, gcorr, (1.f - alpha) * gsem);
    }
}

extern "C" void kernel_launch(void* const* d_in, const int* in_sizes, int n_in,
                              void* d_out, int out_size, void* d_ws, size_t ws_size,
                              hipStream_t stream)
{
    (void)n_in; (void)out_size; (void)ws_size;
    const float* x     = (const float*)d_in[0];
    const float* cw1   = (const float*)d_in[1];
    const float* cb1   = (const float*)d_in[2];
    const float* cw2   = (const float*)d_in[3];
    const float* cb2   = (const float*)d_in[4];
    const float* emb   = (const float*)d_in[5];
    const float* sw1   = (const float*)d_in[6];
    const float* sb1   = (const float*)d_in[7];
    const float* ln_g  = (const float*)d_in[8];
    const float* ln_b  = (const float*)d_in[9];
    const float* sw2   = (const float*)d_in[10];
    const float* sb2   = (const float*)d_in[11];
    const float* sw3   = (const float*)d_in[12];
    const float* sb3   = (const float*)d_in[13];
    const float* thr   = (const float*)d_in[14];
    const float* alpha = (const float*)d_in[15];
    float* out = (float*)d_out;
    float* ws  = (float*)d_ws;
    const int B = in_sizes[0] / (22 * 448);

    hipLaunchKernelGGL(hgc_k1, dim3(2 * B), dim3(512), 0, stream,
                       x, cw1, cb1, emb, sw1, sb1, ws);
    hipLaunchKernelGGL(hgc_k2, dim3(16 * B), dim3(256), 0, stream,
                       ws, cw2, cb2, sw2, sb2, sw3, sb3, ln_g, ln_b, thr, alpha, out);
}

// Round 3
// 125.519 us; speedup vs baseline: 1.5200x; 1.3156x over previous
//
#include <hip/hip_runtime.h>
#include <math.h>

namespace {
constexpr int kN = 22;
constexpr int kF = 448;
constexpr int kNP = kN * kN;          // 484
// kernel1 shared pool (floats): corr role needs 22*452 + 44 = 9988 (39.95 KB)
constexpr int kXStr = 452;            // 452%4==0 (16B rows), 452%32==4 (bank spread)
constexpr int kSm1 = kN * kXStr + 2 * kN;   // 9988
// GEMM role overlays: As [64][36] = 2304, Bs [64][68] = 4352  (6656 total)
constexpr int kAStr = 36;
constexpr int kBStr = 68;
// kernel2
constexpr int kPStr = 68;
}

// =================== kernel 1: projections GEMM + corr ======================
// blocks [0, nGemm): 32x64 SGEMM tiles of C = A(M,448) @ W(448,256)
//   col tiles: 0:a1(cw1[0:448],+cb1) 1:a2(cw1[448:896]) 2:u1(sw1[128:576],+emb@sw1[0:64],+sb1)
//              3:u2(sw1[576:1024],+emb@sw1[64:128])
// blocks [nGemm, nGemm+2B): per-(b,half) corr stats + |corr| rows -> g
__global__ __launch_bounds__(256) void hgc_k1(
    const float* __restrict__ x,
    const float* __restrict__ cw1, const float* __restrict__ cb1,
    const float* __restrict__ emb,
    const float* __restrict__ sw1, const float* __restrict__ sb1,
    float* __restrict__ C, float* __restrict__ g,
    int M, int Mtiles, int nGemm)
{
    __shared__ __align__(16) float sm[kSm1];
    const int tid = threadIdx.x;

    if ((int)blockIdx.x < nGemm) {
        // ---------------- GEMM role ----------------
        float* As = sm;                 // [64][kAStr] transposed: As[k][m]
        float* Bs = sm + 64 * kAStr;    // [64][kBStr]: Bs[k][n]
        const int bm = blockIdx.x % Mtiles;
        const int bn = blockIdx.x / Mtiles;        // 0..3
        const int m0 = bm * 32;

        const float* Wsrc =
            (bn == 0) ? cw1 :
            (bn == 1) ? cw1 + 448 * 64 :
            (bn == 2) ? sw1 + 128 * 64 :
                        sw1 + 576 * 64;

        const int tm = tid & 15;        // m-group: rows tm*2, tm*2+1
        const int tn = tid >> 4;        // n-group: cols tn*4 .. +3
        float acc[2][4];
        #pragma unroll
        for (int i = 0; i < 2; ++i)
            #pragma unroll
            for (int j = 0; j < 4; ++j) acc[i][j] = 0.f;

        for (int k0 = 0; k0 < kF; k0 += 64) {
            // stage A (32 rows x 64 k), transposed
            #pragma unroll
            for (int pass = 0; pass < 2; ++pass) {
                const int idx = tid + pass * 256;       // 512 float4
                const int row = idx >> 4, kq = idx & 15;
                const int m = m0 + row;
                float4 v = {0, 0, 0, 0};
                if (m < M) v = *(const float4*)&x[(size_t)m * kF + k0 + kq * 4];
                As[(kq * 4 + 0) * kAStr + row] = v.x;
                As[(kq * 4 + 1) * kAStr + row] = v.y;
                As[(kq * 4 + 2) * kAStr + row] = v.z;
                As[(kq * 4 + 3) * kAStr + row] = v.w;
            }
            // stage B (64 k x 64 n)
            #pragma unroll
            for (int pass = 0; pass < 4; ++pass) {
                const int idx = tid + pass * 256;       // 1024 float4
                const int k = idx >> 4, nq = idx & 15;
                const float4 v = *(const float4*)&Wsrc[(size_t)(k0 + k) * 64 + nq * 4];
                *(float4*)&Bs[k * kBStr + nq * 4] = v;
            }
            __syncthreads();
            #pragma unroll 8
            for (int k = 0; k < 64; ++k) {
                const float2 a2 = *(const float2*)&As[k * kAStr + tm * 2];
                const float4 b4 = *(const float4*)&Bs[k * kBStr + tn * 4];
                acc[0][0] = fmaf(a2.x, b4.x, acc[0][0]);
                acc[0][1] = fmaf(a2.x, b4.y, acc[0][1]);
                acc[0][2] = fmaf(a2.x, b4.z, acc[0][2]);
                acc[0][3] = fmaf(a2.x, b4.w, acc[0][3]);
                acc[1][0] = fmaf(a2.y, b4.x, acc[1][0]);
                acc[1][1] = fmaf(a2.y, b4.y, acc[1][1]);
                acc[1][2] = fmaf(a2.y, b4.z, acc[1][2]);
                acc[1][3] = fmaf(a2.y, b4.w, acc[1][3]);
            }
            __syncthreads();
        }

        // emb epilogue for u1/u2 tiles: extra K=64 with A=emb[r(m)], B=sw1[0:64 or 64:128]
        if (bn >= 2) {
            const float* W2 = sw1 + (bn == 2 ? 0 : 64) * 64;
            #pragma unroll
            for (int pass = 0; pass < 2; ++pass) {
                const int idx = tid + pass * 256;
                const int row = idx >> 4, kq = idx & 15;
                const int r = (m0 + row) % kN;
                const float4 v = *(const float4*)&emb[(size_t)r * 64 + kq * 4];
                As[(kq * 4 + 0) * kAStr + row] = v.x;
                As[(kq * 4 + 1) * kAStr + row] = v.y;
                As[(kq * 4 + 2) * kAStr + row] = v.z;
                As[(kq * 4 + 3) * kAStr + row] = v.w;
            }
            #pragma unroll
            for (int pass = 0; pass < 4; ++pass) {
                const int idx = tid + pass * 256;
                const int k = idx >> 4, nq = idx & 15;
                const float4 v = *(const float4*)&W2[(size_t)k * 64 + nq * 4];
                *(float4*)&Bs[k * kBStr + nq * 4] = v;
            }
            __syncthreads();
            #pragma unroll 8
            for (int k = 0; k < 64; ++k) {
                const float2 a2 = *(const float2*)&As[k * kAStr + tm * 2];
                const float4 b4 = *(const float4*)&Bs[k * kBStr + tn * 4];
                acc[0][0] = fmaf(a2.x, b4.x, acc[0][0]);
                acc[0][1] = fmaf(a2.x, b4.y, acc[0][1]);
                acc[0][2] = fmaf(a2.x, b4.z, acc[0][2]);
                acc[0][3] = fmaf(a2.x, b4.w, acc[0][3]);
                acc[1][0] = fmaf(a2.y, b4.x, acc[1][0]);
                acc[1][1] = fmaf(a2.y, b4.y, acc[1][1]);
                acc[1][2] = fmaf(a2.y, b4.z, acc[1][2]);
                acc[1][3] = fmaf(a2.y, b4.w, acc[1][3]);
            }
        }

        float4 bias = {0, 0, 0, 0};
        if (bn == 0)      bias = *(const float4*)&cb1[tn * 4];
        else if (bn == 2) bias = *(const float4*)&sb1[tn * 4];
        #pragma unroll
        for (int i = 0; i < 2; ++i) {
            const int m = m0 + tm * 2 + i;
            if (m < M) {
                float4 o;
                o.x = acc[i][0] + bias.x; o.y = acc[i][1] + bias.y;
                o.z = acc[i][2] + bias.z; o.w = acc[i][3] + bias.w;
                *(float4*)&C[(size_t)m * 256 + bn * 64 + tn * 4] = o;
            }
        }
    } else {
        // ---------------- corr role ----------------
        float* smu = sm + kN * kXStr;
        float* sis = smu + kN;
        const int cb = blockIdx.x - nGemm;
        const int b = cb >> 1;
        const int r0 = (cb & 1) * 11;

        const float4* xb4 = (const float4*)(x + (size_t)b * (kN * kF));
        for (int idx = tid; idx < kN * kF / 4; idx += 256) {
            const float4 v = xb4[idx];
            const int r = idx / 112;
            const int k = (idx - r * 112) * 4;
            float* d = sm + r * kXStr + k;
            d[0] = v.x; d[1] = v.y; d[2] = v.z; d[3] = v.w;
        }
        __syncthreads();

        {
            const int wid = tid >> 6, lane = tid & 63;
            for (int r = wid; r < kN; r += 4) {
                const float* row = sm + r * kXStr;
                float s = 0.f;
                #pragma unroll
                for (int c = 0; c < 7; ++c) s += row[c * 64 + lane];
                #pragma unroll
                for (int o = 32; o; o >>= 1) s += __shfl_xor(s, o, 64);
                const float mean = s * (1.f / 448.f);
                float ss = 0.f;
                #pragma unroll
                for (int c = 0; c < 7; ++c) { const float d = row[c * 64 + lane] - mean; ss = fmaf(d, d, ss); }
                #pragma unroll
                for (int o = 32; o; o >>= 1) ss += __shfl_xor(ss, o, 64);
                if (lane == 0) {
                    smu[r] = mean;
                    sis[r] = 1.f / (sqrtf(ss * (1.f / 447.f)) + 1e-8f);   // ddof=1
                }
            }
        }
        __syncthreads();

        for (int p = tid; p < 11 * kN; p += 256) {
            const int pi = p / 22;
            const int i = r0 + pi, j = p - pi * 22;
            const float4* ri = (const float4*)(sm + i * kXStr);
            const float4* rj = (const float4*)(sm + j * kXStr);
            float dot = 0.f;
            for (int q = 0; q < 112; ++q) {
                const float4 a = ri[q], bq = rj[q];
                dot = fmaf(a.x, bq.x, dot); dot = fmaf(a.y, bq.y, dot);
                dot = fmaf(a.z, bq.z, dot); dot = fmaf(a.w, bq.w, dot);
            }
            const float c = (dot - 448.f * smu[i] * smu[j]) * sis[i] * sis[j] * (1.f / 448.f);
            g[(size_t)b * kNP + i * 22 + j] = fabsf(c);
        }
    }
}

// =================== kernel 2: 4 blocks/b, 121 pairs each ===================
__global__ __launch_bounds__(256) void hgc_k2(
    const float* __restrict__ C, const float* __restrict__ g,
    const float* __restrict__ cw2, const float* __restrict__ cb2,
    const float* __restrict__ sw2, const float* __restrict__ sb2,
    const float* __restrict__ sw3, const float* __restrict__ sb3,
    const float* __restrict__ ln_g, const float* __restrict__ ln_b,
    const float* __restrict__ thr, const float* __restrict__ alpha_p,
    float* __restrict__ out)
{
    __shared__ __align__(16) float sp[4 * kN * kPStr];   // a1|a2|u1|u2, padded rows
    __shared__ float sg[kNP];
    __shared__ __align__(16) float sw2s[2048];
    __shared__ float scw2[64], slng[64], slnb[64], ssw3[32], ssb2[32];
    __shared__ float vbuf[32 * 66];

    const int tid = threadIdx.x;
    const int b   = blockIdx.x >> 2;
    const int pb  = blockIdx.x & 3;

    // stage the four 22x64 projection arrays from C rows (b*22+r), col block a*64
    #pragma unroll
    for (int a = 0; a < 4; ++a) {
        float* dst = sp + a * kN * kPStr;
        for (int idx = tid; idx < 352; idx += 256) {
            const int r = idx >> 4, kq = idx & 15;
            const float4 v = *(const float4*)&C[((size_t)(b * 22 + r)) * 256 + a * 64 + kq * 4];
            *(float4*)&dst[r * kPStr + kq * 4] = v;
        }
    }
    for (int idx = tid; idx < kNP; idx += 256) sg[idx] = g[(size_t)b * kNP + idx];
    {
        const float4* s4 = (const float4*)sw2;
        for (int idx = tid; idx < 512; idx += 256)
            *((float4*)(sw2s + idx * 4)) = s4[idx];
    }
    if (tid < 64)       { scw2[tid] = cw2[tid]; slng[tid] = ln_g[tid]; slnb[tid] = ln_b[tid]; }
    else if (tid < 96)  { ssw3[tid - 64] = sw3[tid - 64]; }
    else if (tid < 128) { ssb2[tid - 96] = sb2[tid - 96]; }
    __syncthreads();

    const int pl = tid >> 3;             // local pair slot 0..31
    const int t  = tid & 7;              // lane within pair group
    const float* sa1 = sp;
    const float* sa2 = sp + kN * kPStr;
    const float* su1 = sp + 2 * kN * kPStr;
    const float* su2 = sp + 3 * kN * kPStr;

    for (int ch = 0; ch < 4; ++ch) {
        const int lp = ch * 32 + pl;                 // 0..127
        const bool valid = lp < 121;
        const int p = valid ? (pb * 121 + lp) : 0;   // 484 = 4*121 exactly
        const int i = p / 22, j = p - (p / 22) * 22;

        // correlation edge weight: sigmoid(relu(a1_i + a2_j) . cw2 + cb2)
        float zc = 0.f;
        {
            const float* pa1 = sa1 + i * kPStr + t * 8;
            const float* pa2 = sa2 + j * kPStr + t * 8;
            #pragma unroll
            for (int c = 0; c < 8; ++c) {
                const float h = fmaxf(pa1[c] + pa2[c], 0.f);
                zc = fmaf(h, scw2[t * 8 + c], zc);
            }
            zc += __shfl_xor(zc, 1, 64); zc += __shfl_xor(zc, 2, 64); zc += __shfl_xor(zc, 4, 64);
        }
        const float wc = 1.f / (1.f + __expf(-(zc + cb2[0])));

        // semantic branch
        const int lo = (i < j) ? i : j, hi = (i < j) ? j : i;
        const float* pu1 = su1 + lo * kPStr + t * 8;
        const float* pu2 = su2 + hi * kPStr + t * 8;
        float raw[8];
        float s1 = 0.f;
        #pragma unroll
        for (int c = 0; c < 8; ++c) { raw[c] = pu1[c] + pu2[c]; s1 += raw[c]; }
        s1 += __shfl_xor(s1, 1, 64); s1 += __shfl_xor(s1, 2, 64); s1 += __shfl_xor(s1, 4, 64);
        const float mean = s1 * (1.f / 64.f);
        float s2 = 0.f;
        #pragma unroll
        for (int c = 0; c < 8; ++c) { const float d = raw[c] - mean; s2 = fmaf(d, d, s2); }
        s2 += __shfl_xor(s2, 1, 64); s2 += __shfl_xor(s2, 2, 64); s2 += __shfl_xor(s2, 4, 64);
        const float rstd = rsqrtf(s2 * (1.f / 64.f) + 1e-5f);
        {
            float* vb = vbuf + pl * 66 + t * 8;
            #pragma unroll
            for (int c = 0; c < 8; ++c) {
                const int k = t * 8 + c;
                float v = (raw[c] - mean) * rstd;
                v = fmaf(v, slng[k], slnb[k]);
                vb[c] = fmaxf(v, 0.f);
            }
        }
        __syncthreads();   // vbuf visibility

        // 64x32 GEMV: lane owns outputs o = t*4 .. t*4+3
        float4 acc = {0, 0, 0, 0};
        {
            const float* vb = vbuf + pl * 66;
            for (int k = 0; k < 64; ++k) {
                const float v = vb[k];
                const float4 w = *((const float4*)(sw2s + k * 32 + t * 4));
                acc.x = fmaf(v, w.x, acc.x); acc.y = fmaf(v, w.y, acc.y);
                acc.z = fmaf(v, w.z, acc.z); acc.w = fmaf(v, w.w, acc.w);
            }
        }
        float z2;
        {
            const int o0 = t * 4;
            z2  = fmaxf(acc.x + ssb2[o0 + 0], 0.f) * ssw3[o0 + 0];
            z2 += fmaxf(acc.y + ssb2[o0 + 1], 0.f) * ssw3[o0 + 1];
            z2 += fmaxf(acc.z + ssb2[o0 + 2], 0.f) * ssw3[o0 + 2];
            z2 += fmaxf(acc.w + ssb2[o0 + 3], 0.f) * ssw3[o0 + 3];
            z2 += __shfl_xor(z2, 1, 64); z2 += __shfl_xor(z2, 2, 64); z2 += __shfl_xor(z2, 4, 64);
        }

        if (valid && t == 0) {
            float gsem;
            if (i == j) {
                gsem = 1.f;
            } else {
                // accurate expf: this sigmoid feeds a hard threshold compare
                const float wsem = 1.f / (1.f + expf(-(z2 + sb3[0])));
                const float tt   = 1.f / (1.f + expf(-thr[0]));
                gsem = (wsem > tt) ? wsem : 0.f;
            }
            const float alpha = 1.f / (1.f + __expf(-alpha_p[0]));
            const float gcorr = fmaf(sg[p], wc, (i == j) ? 1.f : 0.f);
            out[(size_t)b * kNP + p] = fmaf(alpha, gcorr, (1.f - alpha) * gsem);
        }
    }
}

extern "C" void kernel_launch(void* const* d_in, const int* in_sizes, int n_in,
                              void* d_out, int out_size, void* d_ws, size_t ws_size,
                              hipStream_t stream)
{
    (void)n_in; (void)out_size; (void)ws_size;
    const float* x     = (const float*)d_in[0];
    const float* cw1   = (const float*)d_in[1];
    const float* cb1   = (const float*)d_in[2];
    const float* cw2   = (const float*)d_in[3];
    const float* cb2   = (const float*)d_in[4];
    const float* emb   = (const float*)d_in[5];
    const float* sw1   = (const float*)d_in[6];
    const float* sb1   = (const float*)d_in[7];
    const float* ln_g  = (const float*)d_in[8];
    const float* ln_b  = (const float*)d_in[9];
    const float* sw2   = (const float*)d_in[10];
    const float* sb2   = (const float*)d_in[11];
    const float* sw3   = (const float*)d_in[12];
    const float* sb3   = (const float*)d_in[13];
    const float* thr   = (const float*)d_in[14];
    const float* alpha = (const float*)d_in[15];
    float* out = (float*)d_out;
    float* ws  = (float*)d_ws;

    const int B = in_sizes[0] / (kN * kF);
    const int M = kN * B;
    const int Mtiles = (M + 31) / 32;
    const int nGemm = Mtiles * 4;

    float* C = ws;                           // M x 256
    float* g = ws + (size_t)M * 256;         // B x 484

    hipLaunchKernelGGL(hgc_k1, dim3(nGemm + 2 * B), dim3(256), 0, stream,
                       x, cw1, cb1, emb, sw1, sb1, C, g, M, Mtiles, nGemm);
    hipLaunchKernelGGL(hgc_k2, dim3(4 * B), dim3(256), 0, stream,
                       C, g, cw2, cb2, sw2, sb2, sw3, sb3, ln_g, ln_b, thr, alpha, out);
}